// Round 1
// 260.783 us; speedup vs baseline: 1.0017x; 1.0017x over previous
//
#include <hip/hip_runtime.h>

// Problem constants
#define BB 128
#define TT 6
#define KK 64
#define DD 8
#define HH 128
#define NSTEP 5
#define LDP 136      // padded LDS row (u16 elems): 272B = 17*16B, 16B-aligned rows
#define PREDSZ (BB*NSTEP*KK*DD)   // 327680

typedef unsigned short u16;
typedef unsigned int   u32;
typedef __attribute__((ext_vector_type(8))) short bf16x8;
typedef __attribute__((ext_vector_type(4))) float f32x4;
typedef __attribute__((ext_vector_type(2))) unsigned int u32x2;
typedef __attribute__((ext_vector_type(2))) _Float16 h2;

union h2u { u32 u; h2 h; };

__device__ __forceinline__ float bf2f(u16 u){
  union { u32 i; float f; } v; v.i = ((u32)u) << 16; return v.f;
}
__device__ __forceinline__ u16 f2bf(float f){
  u32 x = __float_as_uint(f);
  x += 0x7FFFu + ((x >> 16) & 1u);   // RNE
  return (u16)(x >> 16);
}

// ---------------- ws layout (u16 element offsets), all transposed WT[n][k] ----------------
#define O_WIAT 0
#define O_WIBT 16384
#define O_SW1T 32768
#define O_SW2T 49152
#define O_IW2T 65536
#define O_UW2T 81920
#define O_DW1T 98304
#define O_EW2T 114688
#define O_DET  131072
#define O_UW1T 147456   // 128 x 256
#define O_DW2T 180224   // dw2 transposed bf16 [8][128]
#define O_DEB  181248   // 128 f32 (de bias), float index 90624

// GEMM: O(64x128) = A(64x128)@W [*ascale + bias], W frags persistent in regs (4 x bf16x8/thread).
// Wave w owns cols [16w,16w+16); per wave: 4 m-tiles. n = 16w + (lane&15), q = lane>>4.
template<bool RELU>
__device__ __forceinline__ void gemm128(const u16 (*A)[LDP], const bf16x8* bf,
    float ascale, float bias, u16 (*O)[LDP], int l15, int q, int n)
{
#pragma unroll
  for (int mt=0; mt<4; ++mt){
    f32x4 acc = {0.f,0.f,0.f,0.f};
#pragma unroll
    for (int kc=0; kc<4; ++kc){
      bf16x8 af = *(const bf16x8*)&A[(mt<<4)+l15][(kc<<5)+(q<<3)];
      acc = __builtin_amdgcn_mfma_f32_16x16x32_bf16(af, bf[kc], acc, 0,0,0);
    }
#pragma unroll
    for (int e=0; e<4; ++e){
      float v = acc[e]*ascale + bias;
      if (RELU) v = fmaxf(v, 0.f);
      O[(mt<<4)+(q<<2)+e][n] = f2bf(v);              // C/D: col=lane&15, row=q*4+e
    }
  }
}

// Same, but W frags loaded from global ws (L2-hot), bf16 out
template<bool RELU>
__device__ __forceinline__ void gemm128g(const u16 (*A)[LDP], const u16* __restrict__ wt,
    float bias, u16 (*O)[LDP], int l15, int q, int n)
{
  bf16x8 bf[4];
#pragma unroll
  for (int kc=0; kc<4; ++kc) bf[kc] = *(const bf16x8*)(wt + n*128 + (kc<<5) + (q<<3));
#pragma unroll
  for (int mt=0; mt<4; ++mt){
    f32x4 acc = {0.f,0.f,0.f,0.f};
#pragma unroll
    for (int kc=0; kc<4; ++kc){
      bf16x8 af = *(const bf16x8*)&A[(mt<<4)+l15][(kc<<5)+(q<<3)];
      acc = __builtin_amdgcn_mfma_f32_16x16x32_bf16(af, bf[kc], acc, 0,0,0);
    }
#pragma unroll
    for (int e=0; e<4; ++e){
      float v = acc[e] + bias;
      if (RELU) v = fmaxf(v, 0.f);
      O[(mt<<4)+(q<<2)+e][n] = f2bf(v);
    }
  }
}

// K=256 (update MLP layer1): A = [A1 | A2], relu out
__device__ __forceinline__ void gemm256(const u16 (*A1)[LDP], const u16 (*A2)[LDP],
    const bf16x8* bf /*8*/, float bias, u16 (*O)[LDP], int l15, int q, int n)
{
#pragma unroll
  for (int mt=0; mt<4; ++mt){
    f32x4 acc = {0.f,0.f,0.f,0.f};
#pragma unroll
    for (int kc=0; kc<8; ++kc){
      const u16 (*As)[LDP] = (kc<4) ? A1 : A2;
      bf16x8 af = *(const bf16x8*)&As[(mt<<4)+l15][((kc&3)<<5)+(q<<3)];
      acc = __builtin_amdgcn_mfma_f32_16x16x32_bf16(af, bf[kc], acc, 0,0,0);
    }
#pragma unroll
    for (int e=0; e<4; ++e){
      float v = fmaxf(acc[e] + bias, 0.f);
      O[(mt<<4)+(q<<2)+e][n] = f2bf(v);
    }
  }
}

// Fused stage1: one pass over A-frags of P feeds 3 GEMMs:
//   Q = P@wia (f16), R = P@wib + ib1 (f16), S = relu(P@sw1 + sb1) (bf16)
__device__ __forceinline__ void stage1(const u16 (*P)[LDP],
    const bf16x8* fa, const bf16x8* fb, const bf16x8* fs,
    float ib1v, float sb1v,
    u16 (*Q)[LDP], u16 (*R)[LDP], u16 (*S)[LDP], int l15, int q, int n)
{
#pragma unroll
  for (int mt=0; mt<4; ++mt){
    f32x4 aA = {0.f,0.f,0.f,0.f}, aB = {0.f,0.f,0.f,0.f}, aS = {0.f,0.f,0.f,0.f};
#pragma unroll
    for (int kc=0; kc<4; ++kc){
      bf16x8 af = *(const bf16x8*)&P[(mt<<4)+l15][(kc<<5)+(q<<3)];
      aA = __builtin_amdgcn_mfma_f32_16x16x32_bf16(af, fa[kc], aA, 0,0,0);
      aB = __builtin_amdgcn_mfma_f32_16x16x32_bf16(af, fb[kc], aB, 0,0,0);
      aS = __builtin_amdgcn_mfma_f32_16x16x32_bf16(af, fs[kc], aS, 0,0,0);
    }
#pragma unroll
    for (int e=0; e<4; ++e){
      const int row = (mt<<4)+(q<<2)+e;
      _Float16 ha = (_Float16)aA[e];          Q[row][n] = *(const u16*)&ha;
      _Float16 hb = (_Float16)(aB[e]+ib1v);   R[row][n] = *(const u16*)&hb;
      S[row][n] = f2bf(fmaxf(aS[e]+sb1v, 0.f));
    }
  }
}

// Qa := Ssum where Ssum[j,h] = sum_i relu(a[i,h]+b[j,h]); a,b stored f16; out bf16.
// lanes=j, wave w owns cols [16w,16w+16): in-place, wave-disjoint.
// packed f16: + -> v_pk_add_f16, __builtin_elementwise_max -> v_pk_max_f16
__device__ __forceinline__ void interaction(u16 (*Qa)[LDP], const u16 (*Rb)[LDP], int w, int lane)
{
  h2 z; z.x = (_Float16)0.f; z.y = (_Float16)0.f;
#pragma unroll
  for (int p=0; p<4; ++p){
    const int h = (w<<4) + (p<<2);
    u32x2 bv = *(const u32x2*)&Rb[lane][h];
    h2u cb0, cb1; cb0.u = bv.x; cb1.u = bv.y;
    h2 s01 = z, s23 = z, t01 = z, t23 = z;
#pragma unroll 8
    for (int i=0; i<KK; i+=2){
      u32x2 a0 = *(const u32x2*)&Qa[i][h];      // lane-uniform broadcast
      u32x2 a1 = *(const u32x2*)&Qa[i+1][h];
      h2u x0, x1, y0, y1; x0.u = a0.x; x1.u = a0.y; y0.u = a1.x; y1.u = a1.y;
      s01 += __builtin_elementwise_max(x0.h + cb0.h, z);
      s23 += __builtin_elementwise_max(x1.h + cb1.h, z);
      t01 += __builtin_elementwise_max(y0.h + cb0.h, z);
      t23 += __builtin_elementwise_max(y1.h + cb1.h, z);
    }
    s01 += t01; s23 += t23;
    const float f0 = (float)s01.x, f1 = (float)s01.y;
    const float f2 = (float)s23.x, f3 = (float)s23.y;
    u32x2 ov;
    ov.x = (u32)f2bf(f0) | ((u32)f2bf(f1) << 16);
    ov.y = (u32)f2bf(f2) | ((u32)f2bf(f3) << 16);
    *(u32x2*)&Qa[lane][h] = ov;
  }
}

// pred(64x8) = S(64x128,bf16) @ dw2 + db2 -> global out only (off critical path)
__device__ __forceinline__ void dec_out(const u16 (*S)[LDP], const u16* __restrict__ dwt,
    float db2v, float* __restrict__ out, int b, int t, int tid)
{
  const int r = tid>>3, d = tid&7;
  float acc = db2v;
#pragma unroll
  for (int c=0; c<16; ++c){
    bf16x8 hv = *(const bf16x8*)&S[r][c<<3];
    bf16x8 wv = *(const bf16x8*)(dwt + (d<<7) + (c<<3));
#pragma unroll
    for (int j=0; j<8; ++j)
      acc += bf2f((u16)hv[j]) * bf2f((u16)wv[j]);
  }
  out[(size_t)(b*NSTEP + t)*(KK*DD) + (r<<3) + d] = acc;
}

// enc layer1 (K=8) from fp32 pred buffer — used once at start
__device__ __forceinline__ void mlp_in8(const float* pred, const float* __restrict__ W,
    const float* __restrict__ bias, u16 (*O)[LDP], int tid)
{
  const int h = tid & 127, rg = tid >> 7;
  float wv[DD];
#pragma unroll
  for (int d=0; d<DD; ++d) wv[d] = W[d*HH + h];
  const float bv = bias[h];
  for (int rr=0; rr<16; ++rr){
    const int r = (rg<<4) + rr;
    float v = bv;
#pragma unroll
    for (int d=0; d<DD; ++d) v += pred[r*DD + d] * wv[d];
    O[r][h] = f2bf(fmaxf(v, 0.f));
  }
}

// ---------------- prep: stage transposed bf16 weights + fused DE matrix ----------------
__global__ void prep_kernel(
    const float* __restrict__ ew1, const float* __restrict__ eb1,
    const float* __restrict__ ew2, const float* __restrict__ sw1, const float* __restrict__ sw2,
    const float* __restrict__ iw1, const float* __restrict__ iw2, const float* __restrict__ uw1,
    const float* __restrict__ uw2, const float* __restrict__ dw1, const float* __restrict__ dw2,
    const float* __restrict__ db2, u16* __restrict__ ws)
{
  const int idx = blockIdx.x * 256 + threadIdx.x;
  if (idx < 114688){
    const int seg = idx >> 14, r = idx & 16383, n = r >> 7, k = r & 127;
    float v;
    switch (seg){
      case 0: v = iw1[k*HH + n]; break;            // wi_a
      case 1: v = iw1[(HH+k)*HH + n]; break;       // wi_b
      case 2: v = sw1[k*HH + n]; break;
      case 3: v = sw2[k*HH + n]; break;
      case 4: v = iw2[k*HH + n]; break;
      case 5: v = uw2[k*HH + n]; break;
      default: v = dw1[k*HH + n]; break;
    }
    ws[idx] = f2bf(v);
  } else if (idx < 131072){
    const int r = idx - 114688, n = r >> 7, k = r & 127;
    ws[idx] = f2bf(ew2[k*HH + n]);
  } else if (idx < 147456){
    const int r = idx - 131072, n = r >> 7, k = r & 127;   // DE = dw2 @ ew1 (fp32 product)
    float v = 0.f;
#pragma unroll
    for (int d=0; d<DD; ++d) v += dw2[k*DD + d] * ew1[d*HH + n];
    ws[idx] = f2bf(v);
  } else if (idx < 180224){
    const int r = idx - 147456, n = r >> 8, k = r & 255;
    ws[idx] = f2bf(uw1[k*HH + n]);
  } else if (idx < 181248){
    const int r = idx - 180224, d = r >> 7, h = r & 127;
    ws[idx] = f2bf(dw2[h*DD + d]);
  } else if (idx < 181376){
    const int n = idx - 181248;                    // de_bias = db2 @ ew1 + eb1 (fp32)
    float v = eb1[n];
#pragma unroll
    for (int d=0; d<DD; ++d) v += db2[d] * ew1[d*HH + n];
    ((float*)ws)[90624 + n] = v;
  }
}

// ---------------- rollout: 1 block / batch, 5 steps, weights persistent in VGPRs ----------------
// __launch_bounds__(512, 1): grid is 128 blocks <= 256 CUs, so a second resident
// block per CU never materializes — the old (512,2) only capped the register
// allocator at 128 VGPRs, forcing the 144-VGPR persistent weight set to spill to
// scratch (seen as ~24 MB of excess WRITE_SIZE). With min-waves=1 the budget is
// 256 regs/thread and all weight fragments stay resident.
__global__ __launch_bounds__(512, 1) void rollout_kernel(
    const float* __restrict__ gt, const int* __restrict__ rollout,
    const float* __restrict__ ew1, const float* __restrict__ eb1, const float* __restrict__ eb2,
    const float* __restrict__ sb1, const float* __restrict__ sb2,
    const float* __restrict__ ib1, const float* __restrict__ ib2,
    const float* __restrict__ ub1, const float* __restrict__ ub2,
    const float* __restrict__ db1, const float* __restrict__ db2,
    const u16* __restrict__ ws, float* __restrict__ out)
{
  extern __shared__ u16 smem[];
  u16 (*P)[LDP] = (u16(*)[LDP])smem;
  u16 (*Q)[LDP] = (u16(*)[LDP])(smem + KK*LDP);
  u16 (*R)[LDP] = (u16(*)[LDP])(smem + 2*KK*LDP);
  u16 (*S)[LDP] = (u16(*)[LDP])(smem + 3*KK*LDP);
  float* predbuf = (float*)S;                       // overlays S, only used at init

  const int tid = threadIdx.x, b = blockIdx.x;
  const int w = tid >> 6, lane = tid & 63;
  const int l15 = lane & 15, q = lane >> 4;
  const int n = (w << 4) + l15;

  int ns = rollout[0];
  if (ns > TT-1) ns = TT-1;
  if (ns > NSTEP) ns = NSTEP;
  if (ns < 0) ns = 0;

  // ---- persistent weight fragments (7 x 4 + 8 = 36 frags = 144 VGPRs) ----
  bf16x8 F_WIA[4], F_WIB[4], F_SW1[4], F_SW2[4], F_IW2[4], F_UW2[4], F_DW1[4], F_UW1[8];
#pragma unroll
  for (int kc=0; kc<4; ++kc){
    const int o = (kc<<5) + (q<<3);
    F_WIA[kc] = *(const bf16x8*)(ws + O_WIAT + n*128 + o);
    F_WIB[kc] = *(const bf16x8*)(ws + O_WIBT + n*128 + o);
    F_SW1[kc] = *(const bf16x8*)(ws + O_SW1T + n*128 + o);
    F_SW2[kc] = *(const bf16x8*)(ws + O_SW2T + n*128 + o);
    F_IW2[kc] = *(const bf16x8*)(ws + O_IW2T + n*128 + o);
    F_UW2[kc] = *(const bf16x8*)(ws + O_UW2T + n*128 + o);
    F_DW1[kc] = *(const bf16x8*)(ws + O_DW1T + n*128 + o);
  }
#pragma unroll
  for (int kc=0; kc<8; ++kc)
    F_UW1[kc] = *(const bf16x8*)(ws + O_UW1T + n*256 + (kc<<5) + (q<<3));

  // ---- per-thread bias registers (col n) ----
  const float eb2v = eb2[n], sb1v = sb1[n], sb2v = sb2[n];
  const float ib1v = ib1[n], ib2v = ib2[n];
  const float ub1v = ub1[n], ub2v = ub2[n], db1v = db1[n];
  const float dev  = ((const float*)ws)[90624 + n];
  const float db2v = db2[tid & 7];

  // ---- init: targets copy + slots = enc(gt[:,0]) ----
  for (int i=tid; i<NSTEP*KK*DD; i+=512)
    out[PREDSZ + b*(NSTEP*KK*DD) + i] = gt[(size_t)b*(TT*KK*DD) + KK*DD + i];
  { const int r = tid>>3, d = tid&7;
    predbuf[r*DD + d] = gt[(size_t)b*(TT*KK*DD) + r*DD + d]; }
  __syncthreads();
  mlp_in8(predbuf, ew1, eb1, Q, tid);
  __syncthreads();
  gemm128g<false>(Q, ws + O_EW2T, eb2v, P, l15, q, n);   // P = slots
  __syncthreads();

  for (int t=0; t<ns; ++t){
    stage1(P, F_WIA, F_WIB, F_SW1, ib1v, sb1v, Q, R, S, l15, q, n);  // Q=a(f16) R=b+ib1(f16) S=h_self
    __syncthreads();
    interaction(Q, R, w, lane);                                       // Q = Ssum (bf16)
    __syncthreads();
    gemm128<false>(Q, F_IW2, 1.f/64.f, ib2v, R, l15, q, n);           // R = delta_inter
    gemm128<false>(S, F_SW2, 1.f, sb2v, P, l15, q, n);                // P = delta_self
    __syncthreads();
    gemm256(P, R, F_UW1, ub1v, Q, l15, q, n);                         // Q = relu([DS|DI]@uw1+ub1)
    __syncthreads();
    gemm128<false>(Q, F_UW2, 1.f, ub2v, P, l15, q, n);                // P = new slots
    __syncthreads();
    gemm128<true>(P, F_DW1, 1.f, db1v, S, l15, q, n);                 // S = h_dec
    __syncthreads();
    gemm128g<true>(S, ws + O_DET, dev, Q, l15, q, n);                 // Q = relu(S@DE + de_b) = h_enc1
    dec_out(S, ws + O_DW2T, db2v, out, b, t, tid);                    // pred -> out (side branch)
    __syncthreads();
    gemm128g<false>(Q, ws + O_EW2T, eb2v, P, l15, q, n);              // P = re-encoded slots
    __syncthreads();
  }
}

extern "C" void kernel_launch(void* const* d_in, const int* in_sizes, int n_in,
                              void* d_out, int out_size, void* d_ws, size_t ws_size,
                              hipStream_t stream)
{
  const float* gt  = (const float*)d_in[0];
  const int*   rs  = (const int*)d_in[1];
  const float* ew1 = (const float*)d_in[2];
  const float* eb1 = (const float*)d_in[3];
  const float* ew2 = (const float*)d_in[4];
  const float* eb2 = (const float*)d_in[5];
  const float* sw1 = (const float*)d_in[6];
  const float* sb1 = (const float*)d_in[7];
  const float* sw2 = (const float*)d_in[8];
  const float* sb2 = (const float*)d_in[9];
  const float* iw1 = (const float*)d_in[10];
  const float* ib1 = (const float*)d_in[11];
  const float* iw2 = (const float*)d_in[12];
  const float* ib2 = (const float*)d_in[13];
  const float* uw1 = (const float*)d_in[14];
  const float* ub1 = (const float*)d_in[15];
  const float* uw2 = (const float*)d_in[16];
  const float* ub2 = (const float*)d_in[17];
  const float* dw1 = (const float*)d_in[18];
  const float* db1 = (const float*)d_in[19];
  const float* dw2 = (const float*)d_in[20];
  const float* db2 = (const float*)d_in[21];
  float* out = (float*)d_out;
  u16*   ws  = (u16*)d_ws;

  const int smem_bytes = 4 * KK * LDP * (int)sizeof(u16);  // 69632
  (void)hipFuncSetAttribute((const void*)rollout_kernel,
                            hipFuncAttributeMaxDynamicSharedMemorySize, smem_bytes);

  hipLaunchKernelGGL(prep_kernel, dim3(709), dim3(256), 0, stream,
                     ew1, eb1, ew2, sw1, sw2, iw1, iw2, uw1, uw2, dw1, dw2, db2, ws);
  hipLaunchKernelGGL(rollout_kernel, dim3(BB), dim3(512), smem_bytes, stream,
                     gt, rs, ew1, eb1, eb2, sb1, sb2, ib1, ib2, ub1, ub2,
                     db1, db2, ws, out);
}